// Round 14
// baseline (768.982 us; speedup 1.0000x reference)
//
#include <hip/hip_runtime.h>
#include <hip/hip_bf16.h>
#include <cstdint>

// SNN: Poisson encode (noise < x) -> [T=32] { h = sp@W1^T; v+=h; spike=(v>1); v-=spike; logits += spike@W2^T }
// B=8192, T=32, D_IN=784 (pad K to 800 = 25x32), D_H=100 (pad N to 128), D_OUT=10.
//
// v14: FULL fusion with v13's proven phase structure.
//   Grid 512 x 256thr (2 blocks/CU). Block = 16 b-rows x 128 h x ALL t,
//   t-pair inner loop (16 iters). Per iter:
//     PACK(tp): ballot-pack t0/t1 spikes -> sB[tp&1][2][16*50]  (v13 mapping)
//     LOADPAIR(tp+1): 26 nontemporal float4 noise loads (fly through barrier)
//     raw "lgkmcnt(0); s_barrier"  (NO vmcnt drain -- prefetch stays in flight)
//     GEMM(tp): expand bits (v13 expander) + MFMA vs wf (L2) + sequential IF
//   x in registers (read once); v/cnt in registers; logits epilogue in-block.
//   No H buffer, no scan kernel, no bits traffic: HBM = 822MB noise + 26MB x.
//   VGPR ~215 (<256 cap, no spill); LDS 17KB; stride-25 dword LDS reads
//   (16 distinct banks, conflict-free).

typedef __attribute__((ext_vector_type(8))) short bf16x8;
typedef __attribute__((ext_vector_type(4))) float f32x4;

#define D_IN 784
#define NB 8192
#define KT 25   // K tiles of 32 (800 padded)
#define DH 100
#define ROWS 16

// ---------------- K0: pack W1 into fragment-ready bf16 hi/lo ----------------
// Fragment f = (kt*8 + nt), stored as [f][hi(512 ushorts) | lo(512 ushorts)].
// B-slot(lane l, elem j): n = nt*16 + (l&15), i = kt*32 + (l>>4)*8 + j.
__global__ void prep_w1(const float* __restrict__ W1, unsigned short* __restrict__ wf) {
    int idx = blockIdx.x * 256 + threadIdx.x;           // 25*8*64 = 12800
    if (idx >= KT * 8 * 64) return;
    int l  = idx & 63;
    int nt = (idx >> 6) & 7;
    int kt = idx >> 9;
    int n  = nt * 16 + (l & 15);
    int i0 = kt * 32 + (l >> 4) * 8;
    size_t fbase = (size_t)(kt * 8 + nt) * 1024;
    #pragma unroll
    for (int j = 0; j < 8; ++j) {
        int i = i0 + j;
        float w = (n < DH && i < D_IN) ? W1[n * D_IN + i] : 0.f;
        uint32_t ub = __float_as_uint(w);
        uint32_t rh = ub + 0x7FFFu + ((ub >> 16) & 1u);
        unsigned short h = (unsigned short)(rh >> 16);
        float hf = __uint_as_float(((uint32_t)h) << 16);
        float resid = w - hf;
        uint32_t ul = __float_as_uint(resid);
        uint32_t rl = ul + 0x7FFFu + ((ul >> 16) & 1u);
        unsigned short lo = (unsigned short)(rl >> 16);
        wf[fbase + l * 8 + j]       = h;
        wf[fbase + 512 + l * 8 + j] = lo;
    }
}

// ---------------- K1: fully-fused SNN (v14) ----------------
// Pack mapping (v13-verbatim): thread's f4-slot s = p*256+tid (13 passes,
// valid s < 16*196=3136); ushort-group g = p*64 + wave*16 + u (valid g < 784),
// row = g/49, colu = g%49 -> sB[buf][t01][row*50+colu]; stored bit q <-> float
// offset f in 16-group: q = 4*(f&3) + (f>>2).
// Expand (v13-verbatim): lg=lane>>4, qe0=(lg&1)*2+(lg>>1)*16; dword d:
// qe = qe0 + (d&1)*8 + (d>>1); bits {qe, qe+4}.
__global__ __launch_bounds__(256, 2) void snn_all(const float* __restrict__ x,
                                                  const float* __restrict__ noise,
                                                  const unsigned short* __restrict__ wf,
                                                  const float* __restrict__ W2,
                                                  float* __restrict__ out) {
    __shared__ __align__(4) unsigned short sB[2][2][ROWS * 50];  // 6.4KB
    __shared__ float w2s[1000];
    __shared__ float cbuf[ROWS][104];
    const int tid  = threadIdx.x;
    const int lane = tid & 63;
    const int wave = tid >> 6;
    const int b0   = blockIdx.x * ROWS;
    const int u    = lane & 15;
    const int lg   = lane >> 4;
    const int qe0  = (lg & 1) * 2 + (lg >> 1) * 16;

    if (tid < 64) {                                   // k-pad all 4 bit-tiles
        (&sB[0][0][0])[(tid >> 4) * (ROWS * 50) + (tid & 15) * 50 + 49] = 0;
    }
    for (int i = tid; i < 1000; i += 256) w2s[i] = W2[i];

    int fo4[13];
    #pragma unroll
    for (int p = 0; p < 13; ++p) {
        const int s = p * 256 + tid;
        fo4[p] = (s < ROWS * 196) ? s * 4 : 0;        // clamp; store guarded by g<784
    }

    const float* xb     = x + (size_t)b0 * D_IN;
    const float* nbase  = noise + (size_t)b0 * D_IN;
    const size_t tstride = (size_t)NB * D_IN;

    f32x4 xr[13];
    #pragma unroll
    for (int p = 0; p < 13; ++p) xr[p] = *reinterpret_cast<const f32x4*>(xb + fo4[p]);

    f32x4 t0r[13], t1r[13];
    auto LOADPAIR = [&](int tp) {
        const float* n0 = nbase + (size_t)(2 * tp) * tstride;
        const float* n1 = n0 + tstride;
        #pragma unroll
        for (int p = 0; p < 13; ++p) {
            t0r[p] = __builtin_nontemporal_load(reinterpret_cast<const f32x4*>(n0 + fo4[p]));
            t1r[p] = __builtin_nontemporal_load(reinterpret_cast<const f32x4*>(n1 + fo4[p]));
        }
    };
    auto PACK = [&](int buf) {
        #pragma unroll
        for (int p = 0; p < 13; ++p) {
            const unsigned long long a0 = __ballot(t0r[p][0] < xr[p][0]);
            const unsigned long long a1 = __ballot(t0r[p][1] < xr[p][1]);
            const unsigned long long a2 = __ballot(t0r[p][2] < xr[p][2]);
            const unsigned long long a3 = __ballot(t0r[p][3] < xr[p][3]);
            const unsigned long long c0 = __ballot(t1r[p][0] < xr[p][0]);
            const unsigned long long c1 = __ballot(t1r[p][1] < xr[p][1]);
            const unsigned long long c2 = __ballot(t1r[p][2] < xr[p][2]);
            const unsigned long long c3 = __ballot(t1r[p][3] < xr[p][3]);
            const int g = p * 64 + wave * 16 + u;
            if (lane < 16 && g < ROWS * 49) {
                const uint32_t v0 = (uint32_t)((a0 >> (4 * u)) & 15ull)
                                  | ((uint32_t)((a1 >> (4 * u)) & 15ull) << 4)
                                  | ((uint32_t)((a2 >> (4 * u)) & 15ull) << 8)
                                  | ((uint32_t)((a3 >> (4 * u)) & 15ull) << 12);
                const uint32_t v1 = (uint32_t)((c0 >> (4 * u)) & 15ull)
                                  | ((uint32_t)((c1 >> (4 * u)) & 15ull) << 4)
                                  | ((uint32_t)((c2 >> (4 * u)) & 15ull) << 8)
                                  | ((uint32_t)((c3 >> (4 * u)) & 15ull) << 12);
                const uint32_t row = ((uint32_t)g * 42800u) >> 21;   // g/49 exact
                const int off = (int)row * 50 + (g - (int)row * 49);
                sB[buf][0][off] = (unsigned short)v0;
                sB[buf][1][off] = (unsigned short)v1;
            }
        }
    };

    f32x4 v[2], cnt[2];
    #pragma unroll
    for (int n = 0; n < 2; ++n) { v[n] = (f32x4){0,0,0,0}; cnt[n] = (f32x4){0,0,0,0}; }

    LOADPAIR(0);
    for (int tp = 0; tp < 16; ++tp) {
        const int buf = tp & 1;
        PACK(buf);                                    // waits its loads (vmcnt auto)
        if (tp < 15) LOADPAIR(tp + 1);                // prefetch: flies through barrier
        asm volatile("s_waitcnt lgkmcnt(0)\n\ts_barrier" ::: "memory");  // NO vmcnt drain

        // ---- GEMM(tp): tile 16 rows x 128 h, wave owns ntiles {2w, 2w+1} ----
        const uint32_t* s0 = reinterpret_cast<const uint32_t*>(&sB[buf][0][0]);
        const uint32_t* s1 = reinterpret_cast<const uint32_t*>(&sB[buf][1][0]);
        f32x4 acc[2][2];   // [t][ntl]
        acc[0][0] = (f32x4){0,0,0,0}; acc[0][1] = (f32x4){0,0,0,0};
        acc[1][0] = (f32x4){0,0,0,0}; acc[1][1] = (f32x4){0,0,0,0};
        #pragma unroll
        for (int kt = 0; kt < KT; ++kt) {
            const uint32_t g0 = s0[u * 25 + kt];      // stride-25 dwords: conflict-free
            const uint32_t g1 = s1[u * 25 + kt];
            union { uint32_t uu[4]; bf16x8 vv; } pk0, pk1;
            #pragma unroll
            for (int d = 0; d < 4; ++d) {
                const int qe = qe0 + (d & 1) * 8 + (d >> 1);
                pk0.uu[d] = ((g0 >> qe) & 1u) * 0x3F80u | ((g0 >> (qe + 4)) & 1u) * 0x3F800000u;
                pk1.uu[d] = ((g1 >> qe) & 1u) * 0x3F80u | ((g1 >> (qe + 4)) & 1u) * 0x3F800000u;
            }
            #pragma unroll
            for (int ntl = 0; ntl < 2; ++ntl) {
                const size_t fo = (size_t)(kt * 8 + wave * 2 + ntl) * 1024 + lane * 8;
                const bf16x8 bhi = *reinterpret_cast<const bf16x8*>(wf + fo);
                const bf16x8 blo = *reinterpret_cast<const bf16x8*>(wf + fo + 512);
                acc[0][ntl] = __builtin_amdgcn_mfma_f32_16x16x32_bf16(pk0.vv, bhi, acc[0][ntl], 0, 0, 0);
                acc[0][ntl] = __builtin_amdgcn_mfma_f32_16x16x32_bf16(pk0.vv, blo, acc[0][ntl], 0, 0, 0);
                acc[1][ntl] = __builtin_amdgcn_mfma_f32_16x16x32_bf16(pk1.vv, bhi, acc[1][ntl], 0, 0, 0);
                acc[1][ntl] = __builtin_amdgcn_mfma_f32_16x16x32_bf16(pk1.vv, blo, acc[1][ntl], 0, 0, 0);
            }
        }
        // ---- IF update: t0 then t1 (exact reference semantics) ----
        #pragma unroll
        for (int ntl = 0; ntl < 2; ++ntl)
            #pragma unroll
            for (int r = 0; r < 4; ++r) {
                float vv = v[ntl][r] + acc[0][ntl][r];
                float s  = (vv - 1.0f > 0.0f) ? 1.0f : 0.0f;
                vv -= s;  cnt[ntl][r] += s;
                float vw = vv + acc[1][ntl][r];
                float s2 = (vw - 1.0f > 0.0f) ? 1.0f : 0.0f;
                v[ntl][r] = vw - s2;  cnt[ntl][r] += s2;
            }
        // no second barrier needed: each wave's sB reads completed before its
        // next PACK (lgkmcnt before MFMA use), and PACK(tp+1) targets buf^1.
    }

    // ---- epilogue: cnt -> cbuf, logits = cnt @ W2^T ----
    // C/D layout: col = u (h = (wave*2+ntl)*16 + u), row = lg*4 + r
    #pragma unroll
    for (int ntl = 0; ntl < 2; ++ntl) {
        const int col = (wave * 2 + ntl) * 16 + u;
        if (col < DH) {
            #pragma unroll
            for (int r = 0; r < 4; ++r)
                cbuf[lg * 4 + r][col] = cnt[ntl][r];
        }
    }
    __syncthreads();
    if (tid < ROWS * 10) {
        const int row = tid / 10, o = tid % 10;
        float s = 0.f;
        for (int hh = 0; hh < DH; ++hh) s += cbuf[row][hh] * w2s[o * DH + hh];
        out[(size_t)(b0 + row) * 10 + o] = s;
    }
}

extern "C" void kernel_launch(void* const* d_in, const int* in_sizes, int n_in,
                              void* d_out, int out_size, void* d_ws, size_t ws_size,
                              hipStream_t stream) {
    const float* x     = (const float*)d_in[0];   // [8192,784]
    const float* noise = (const float*)d_in[1];   // [32,8192,784]
    const float* W1    = (const float*)d_in[2];   // [100,784]
    const float* W2    = (const float*)d_in[3];   // [10,100]
    float* out = (float*)d_out;                   // [8192,10]

    unsigned short* wf = (unsigned short*)d_ws;   // 400 KB W1 frags

    prep_w1<<<50, 256, 0, stream>>>(W1, wf);
    snn_all<<<512, 256, 0, stream>>>(x, noise, wf, W2, out);
}

// Round 15
// 452.508 us; speedup vs baseline: 1.6994x; 1.6994x over previous
//
#include <hip/hip_runtime.h>
#include <hip/hip_bf16.h>
#include <cstdint>

// SNN: Poisson encode (noise < x) -> [T=32] { h = sp@W1^T; v+=h; spike=(v>1); v-=spike; logits += spike@W2^T }
// B=8192, T=32, D_IN=784 (pad K to 800 = 25x32), D_H=100 (pad N to 128), D_OUT=10.
//
// v15: v14 structure, allocator unshackled (launch_bounds(256) only -> up to
//   256 VGPR, ~1 block/CU). v14's (256,2) made the allocator cap at 128 VGPR
//   and spill 96MB to scratch (WRITE_SIZE signature). Live set ~215 VGPR.
//   Grid 512 x 256thr. Block = 16 b-rows x 128 h x ALL t, t-pair loop:
//     PACK(tp) -> LOADPAIR(tp+1) (prefetch flies through barrier) ->
//     raw "lgkmcnt(0); s_barrier" (NO vmcnt drain) -> GEMM(tp) + IF in regs.
//   x in registers; logits epilogue in-block. HBM = 822MB noise + 26MB x.

typedef __attribute__((ext_vector_type(8))) short bf16x8;
typedef __attribute__((ext_vector_type(4))) float f32x4;

#define D_IN 784
#define NB 8192
#define KT 25   // K tiles of 32 (800 padded)
#define DH 100
#define ROWS 16

// ---------------- K0: pack W1 into fragment-ready bf16 hi/lo ----------------
// Fragment f = (kt*8 + nt), stored as [f][hi(512 ushorts) | lo(512 ushorts)].
// B-slot(lane l, elem j): n = nt*16 + (l&15), i = kt*32 + (l>>4)*8 + j.
__global__ void prep_w1(const float* __restrict__ W1, unsigned short* __restrict__ wf) {
    int idx = blockIdx.x * 256 + threadIdx.x;           // 25*8*64 = 12800
    if (idx >= KT * 8 * 64) return;
    int l  = idx & 63;
    int nt = (idx >> 6) & 7;
    int kt = idx >> 9;
    int n  = nt * 16 + (l & 15);
    int i0 = kt * 32 + (l >> 4) * 8;
    size_t fbase = (size_t)(kt * 8 + nt) * 1024;
    #pragma unroll
    for (int j = 0; j < 8; ++j) {
        int i = i0 + j;
        float w = (n < DH && i < D_IN) ? W1[n * D_IN + i] : 0.f;
        uint32_t ub = __float_as_uint(w);
        uint32_t rh = ub + 0x7FFFu + ((ub >> 16) & 1u);
        unsigned short h = (unsigned short)(rh >> 16);
        float hf = __uint_as_float(((uint32_t)h) << 16);
        float resid = w - hf;
        uint32_t ul = __float_as_uint(resid);
        uint32_t rl = ul + 0x7FFFu + ((ul >> 16) & 1u);
        unsigned short lo = (unsigned short)(rl >> 16);
        wf[fbase + l * 8 + j]       = h;
        wf[fbase + 512 + l * 8 + j] = lo;
    }
}

// ---------------- K1: fully-fused SNN (v15 = v14, bounds relaxed) ----------------
// Pack mapping (verified): thread's f4-slot s = p*256+tid (13 passes,
// valid s < 16*196=3136); ushort-group g = p*64 + wave*16 + u (valid g < 784),
// row = g/49, colu = g%49 -> sB[buf][t01][row*50+colu]; stored bit q <-> float
// offset f in 16-group: q = 4*(f&3) + (f>>2).
// Expand (verified): lg=lane>>4, qe0=(lg&1)*2+(lg>>1)*16; dword d:
// qe = qe0 + (d&1)*8 + (d>>1); bits {qe, qe+4}.
__global__ __launch_bounds__(256) void snn_all(const float* __restrict__ x,
                                               const float* __restrict__ noise,
                                               const unsigned short* __restrict__ wf,
                                               const float* __restrict__ W2,
                                               float* __restrict__ out) {
    __shared__ __align__(4) unsigned short sB[2][2][ROWS * 50];  // 6.4KB
    __shared__ float w2s[1000];
    __shared__ float cbuf[ROWS][104];
    const int tid  = threadIdx.x;
    const int lane = tid & 63;
    const int wave = tid >> 6;
    const int b0   = blockIdx.x * ROWS;
    const int u    = lane & 15;
    const int lg   = lane >> 4;
    const int qe0  = (lg & 1) * 2 + (lg >> 1) * 16;

    if (tid < 64) {                                   // k-pad all 4 bit-tiles
        (&sB[0][0][0])[(tid >> 4) * (ROWS * 50) + (tid & 15) * 50 + 49] = 0;
    }
    for (int i = tid; i < 1000; i += 256) w2s[i] = W2[i];

    int fo4[13];
    #pragma unroll
    for (int p = 0; p < 13; ++p) {
        const int s = p * 256 + tid;
        fo4[p] = (s < ROWS * 196) ? s * 4 : 0;        // clamp; store guarded by g<784
    }

    const float* xb     = x + (size_t)b0 * D_IN;
    const float* nbase  = noise + (size_t)b0 * D_IN;
    const size_t tstride = (size_t)NB * D_IN;

    f32x4 xr[13];
    #pragma unroll
    for (int p = 0; p < 13; ++p) xr[p] = *reinterpret_cast<const f32x4*>(xb + fo4[p]);

    f32x4 t0r[13], t1r[13];
    auto LOADPAIR = [&](int tp) {
        const float* n0 = nbase + (size_t)(2 * tp) * tstride;
        const float* n1 = n0 + tstride;
        #pragma unroll
        for (int p = 0; p < 13; ++p) {
            t0r[p] = __builtin_nontemporal_load(reinterpret_cast<const f32x4*>(n0 + fo4[p]));
            t1r[p] = __builtin_nontemporal_load(reinterpret_cast<const f32x4*>(n1 + fo4[p]));
        }
    };
    auto PACK = [&](int buf) {
        #pragma unroll
        for (int p = 0; p < 13; ++p) {
            const unsigned long long a0 = __ballot(t0r[p][0] < xr[p][0]);
            const unsigned long long a1 = __ballot(t0r[p][1] < xr[p][1]);
            const unsigned long long a2 = __ballot(t0r[p][2] < xr[p][2]);
            const unsigned long long a3 = __ballot(t0r[p][3] < xr[p][3]);
            const unsigned long long c0 = __ballot(t1r[p][0] < xr[p][0]);
            const unsigned long long c1 = __ballot(t1r[p][1] < xr[p][1]);
            const unsigned long long c2 = __ballot(t1r[p][2] < xr[p][2]);
            const unsigned long long c3 = __ballot(t1r[p][3] < xr[p][3]);
            const int g = p * 64 + wave * 16 + u;
            if (lane < 16 && g < ROWS * 49) {
                const uint32_t v0 = (uint32_t)((a0 >> (4 * u)) & 15ull)
                                  | ((uint32_t)((a1 >> (4 * u)) & 15ull) << 4)
                                  | ((uint32_t)((a2 >> (4 * u)) & 15ull) << 8)
                                  | ((uint32_t)((a3 >> (4 * u)) & 15ull) << 12);
                const uint32_t v1 = (uint32_t)((c0 >> (4 * u)) & 15ull)
                                  | ((uint32_t)((c1 >> (4 * u)) & 15ull) << 4)
                                  | ((uint32_t)((c2 >> (4 * u)) & 15ull) << 8)
                                  | ((uint32_t)((c3 >> (4 * u)) & 15ull) << 12);
                const uint32_t row = ((uint32_t)g * 42800u) >> 21;   // g/49 exact
                const int off = (int)row * 50 + (g - (int)row * 49);
                sB[buf][0][off] = (unsigned short)v0;
                sB[buf][1][off] = (unsigned short)v1;
            }
        }
    };

    f32x4 v[2], cnt[2];
    #pragma unroll
    for (int n = 0; n < 2; ++n) { v[n] = (f32x4){0,0,0,0}; cnt[n] = (f32x4){0,0,0,0}; }

    LOADPAIR(0);
    for (int tp = 0; tp < 16; ++tp) {
        const int buf = tp & 1;
        PACK(buf);                                    // waits its loads (vmcnt auto)
        if (tp < 15) LOADPAIR(tp + 1);                // prefetch: flies through barrier
        asm volatile("s_waitcnt lgkmcnt(0)\n\ts_barrier" ::: "memory");  // NO vmcnt drain

        // ---- GEMM(tp): tile 16 rows x 128 h, wave owns ntiles {2w, 2w+1} ----
        const uint32_t* s0 = reinterpret_cast<const uint32_t*>(&sB[buf][0][0]);
        const uint32_t* s1 = reinterpret_cast<const uint32_t*>(&sB[buf][1][0]);
        f32x4 acc[2][2];   // [t][ntl]
        acc[0][0] = (f32x4){0,0,0,0}; acc[0][1] = (f32x4){0,0,0,0};
        acc[1][0] = (f32x4){0,0,0,0}; acc[1][1] = (f32x4){0,0,0,0};
        #pragma unroll
        for (int kt = 0; kt < KT; ++kt) {
            const uint32_t g0 = s0[u * 25 + kt];      // stride-25 dwords: conflict-free
            const uint32_t g1 = s1[u * 25 + kt];
            union { uint32_t uu[4]; bf16x8 vv; } pk0, pk1;
            #pragma unroll
            for (int d = 0; d < 4; ++d) {
                const int qe = qe0 + (d & 1) * 8 + (d >> 1);
                pk0.uu[d] = ((g0 >> qe) & 1u) * 0x3F80u | ((g0 >> (qe + 4)) & 1u) * 0x3F800000u;
                pk1.uu[d] = ((g1 >> qe) & 1u) * 0x3F80u | ((g1 >> (qe + 4)) & 1u) * 0x3F800000u;
            }
            #pragma unroll
            for (int ntl = 0; ntl < 2; ++ntl) {
                const size_t fo = (size_t)(kt * 8 + wave * 2 + ntl) * 1024 + lane * 8;
                const bf16x8 bhi = *reinterpret_cast<const bf16x8*>(wf + fo);
                const bf16x8 blo = *reinterpret_cast<const bf16x8*>(wf + fo + 512);
                acc[0][ntl] = __builtin_amdgcn_mfma_f32_16x16x32_bf16(pk0.vv, bhi, acc[0][ntl], 0, 0, 0);
                acc[0][ntl] = __builtin_amdgcn_mfma_f32_16x16x32_bf16(pk0.vv, blo, acc[0][ntl], 0, 0, 0);
                acc[1][ntl] = __builtin_amdgcn_mfma_f32_16x16x32_bf16(pk1.vv, bhi, acc[1][ntl], 0, 0, 0);
                acc[1][ntl] = __builtin_amdgcn_mfma_f32_16x16x32_bf16(pk1.vv, blo, acc[1][ntl], 0, 0, 0);
            }
        }
        // ---- IF update: t0 then t1 (exact reference semantics) ----
        #pragma unroll
        for (int ntl = 0; ntl < 2; ++ntl)
            #pragma unroll
            for (int r = 0; r < 4; ++r) {
                float vv = v[ntl][r] + acc[0][ntl][r];
                float s  = (vv - 1.0f > 0.0f) ? 1.0f : 0.0f;
                vv -= s;  cnt[ntl][r] += s;
                float vw = vv + acc[1][ntl][r];
                float s2 = (vw - 1.0f > 0.0f) ? 1.0f : 0.0f;
                v[ntl][r] = vw - s2;  cnt[ntl][r] += s2;
            }
        // single barrier per iter is WAR-safe: PACK(tp+1) targets buf^1, and
        // all waves' sB[buf] reads completed before they reach the next barrier.
    }

    // ---- epilogue: cnt -> cbuf, logits = cnt @ W2^T ----
    // C/D layout: col = u (h = (wave*2+ntl)*16 + u), row = lg*4 + r
    #pragma unroll
    for (int ntl = 0; ntl < 2; ++ntl) {
        const int col = (wave * 2 + ntl) * 16 + u;
        if (col < DH) {
            #pragma unroll
            for (int r = 0; r < 4; ++r)
                cbuf[lg * 4 + r][col] = cnt[ntl][r];
        }
    }
    __syncthreads();
    if (tid < ROWS * 10) {
        const int row = tid / 10, o = tid % 10;
        float s = 0.f;
        for (int hh = 0; hh < DH; ++hh) s += cbuf[row][hh] * w2s[o * DH + hh];
        out[(size_t)(b0 + row) * 10 + o] = s;
    }
}

extern "C" void kernel_launch(void* const* d_in, const int* in_sizes, int n_in,
                              void* d_out, int out_size, void* d_ws, size_t ws_size,
                              hipStream_t stream) {
    const float* x     = (const float*)d_in[0];   // [8192,784]
    const float* noise = (const float*)d_in[1];   // [32,8192,784]
    const float* W1    = (const float*)d_in[2];   // [100,784]
    const float* W2    = (const float*)d_in[3];   // [10,100]
    float* out = (float*)d_out;                   // [8192,10]

    unsigned short* wf = (unsigned short*)d_ws;   // 400 KB W1 frags

    prep_w1<<<50, 256, 0, stream>>>(W1, wf);
    snn_all<<<512, 256, 0, stream>>>(x, noise, wf, W2, out);
}

// Round 16
// 317.805 us; speedup vs baseline: 2.4197x; 1.4239x over previous
//
#include <hip/hip_runtime.h>
#include <hip/hip_bf16.h>
#include <cstdint>

// SNN: Poisson encode (noise < x) -> [T=32] { h = sp@W1^T; v+=h; spike=(v>1); v-=spike; logits += spike@W2^T }
// B=8192, T=32, D_IN=784 (pad K to 800 = 25x32), D_H=100 (pad N to 128), D_OUT=10.
//
// v16 = v12 RESTORED (best: 317us). Session post-mortem:
//   - v12 sits at ~95% of the measured ~3.3TB/s effective read ceiling
//     (observed across 6 structurally different kernels this session;
//     m13's "6.29TB/s copy" is FETCH+WRITE, i.e. ~3.15TB/s read).
//   - Bytes: 848MB irreducible reads (noise exact-f32 compare; line-granular
//     fetch defeats partial reads) + 210MB H round-trip. Removing H needs
//     full fusion; 6 fused variants (v8,v9,v10,v11,v14,v15) all lost to the
//     register/occupancy/VALU-replication trilemma (best fused: 452us).
//   Structure: K0 prep_w1 (W1 -> bf16 hi/lo MFMA-B frags, exact f32 = hi+lo),
//   K1 t-pair pack+GEMM (x f4 read once per pass for 2 noise compares; wf
//   fragment read once per kt for 2 t's; ballot bit-pack -> conflict-free LDS;
//   verified expander), K2 IF-scan + logits (H [b][t][100] contiguous rows).

typedef __attribute__((ext_vector_type(8))) short bf16x8;
typedef __attribute__((ext_vector_type(4))) float f32x4;

#define D_IN 784
#define NB 8192
#define KT 25   // K tiles of 32 (800 padded)
#define DH 100

// ---------------- K0: pack W1 into fragment-ready bf16 hi/lo ----------------
// Fragment f = (kt*8 + nt), stored as [f][hi(512 ushorts) | lo(512 ushorts)].
// B-slot(lane l, elem j): n = nt*16 + (l&15), i = kt*32 + (l>>4)*8 + j.
__global__ void prep_w1(const float* __restrict__ W1, unsigned short* __restrict__ wf) {
    int idx = blockIdx.x * 256 + threadIdx.x;           // 25*8*64 = 12800
    if (idx >= KT * 8 * 64) return;
    int l  = idx & 63;
    int nt = (idx >> 6) & 7;
    int kt = idx >> 9;
    int n  = nt * 16 + (l & 15);
    int i0 = kt * 32 + (l >> 4) * 8;
    size_t fbase = (size_t)(kt * 8 + nt) * 1024;
    #pragma unroll
    for (int j = 0; j < 8; ++j) {
        int i = i0 + j;
        float w = (n < DH && i < D_IN) ? W1[n * D_IN + i] : 0.f;
        uint32_t ub = __float_as_uint(w);
        uint32_t rh = ub + 0x7FFFu + ((ub >> 16) & 1u);
        unsigned short h = (unsigned short)(rh >> 16);
        float hf = __uint_as_float(((uint32_t)h) << 16);
        float resid = w - hf;
        uint32_t ul = __float_as_uint(resid);
        uint32_t rl = ul + 0x7FFFu + ((ul >> 16) & 1u);
        unsigned short lo = (unsigned short)(rl >> 16);
        wf[fbase + l * 8 + j]       = h;
        wf[fbase + 512 + l * 8 + j] = lo;
    }
}

__device__ __forceinline__ f32x4 ldnt(const float* p) {
    return __builtin_nontemporal_load(reinterpret_cast<const f32x4*>(p));
}
__device__ __forceinline__ f32x4 ld(const float* p) {
    return *reinterpret_cast<const f32x4*>(p);
}

// ---------------- K1: t-pair pack+GEMM ----------------
// Pack mapping (verified): pass p: thread owns f4 = p*512+tid (49x512 = 25088
// = 128x196 exact); ushort-group g = p*128 + wave*16 + u, row = g/49,
// colu = g%49; stored bit q <-> float offset f in 16-group: q = 4*(f&3)+(f>>2).
// Expand (verified): lg=lane>>4, qe0=(lg&1)*2+(lg>>1)*16; dword d:
// qe = qe0 + (d&1)*8 + (d>>1); bits {qe, qe+4}.
__global__ __launch_bounds__(512) void snn_gemm2(const float* __restrict__ x,
                                                 const float* __restrict__ noise,
                                                 const unsigned short* __restrict__ wf,
                                                 float* __restrict__ H) {
    __shared__ __align__(4) unsigned short sB[2][128 * 50];   // 2 x 12.8KB
    const int tid  = threadIdx.x;
    const int lane = tid & 63;
    const int wave = tid >> 6;
    const int L     = blockIdx.x;
    const int btile = (L & 7) * 8 + ((L >> 3) & 7);   // XCD swizzle: x slice 3.2MB/XCD
    const int tp    = L >> 6;                          // t-pair 0..15
    const int b0    = btile * 128;
    const int u     = lane & 15;
    const int lg    = lane >> 4;
    const int Mhalf = wave >> 2;       // 0..1 (64 rows each)
    const int Nq    = wave & 3;        // 0..3 (ntiles Nq*2, Nq*2+1)

    if (tid < 256) sB[tid >> 7][(tid & 127) * 50 + 49] = 0;   // k-pad both tiles

    const float* xb    = x + (size_t)b0 * D_IN;
    const float* nb0   = noise + (size_t)(2 * tp) * ((size_t)NB * D_IN) + (size_t)b0 * D_IN;
    const float* nb1   = nb0 + (size_t)NB * D_IN;

    // ---- pack phase: 49 passes, x loaded once per pass ----
    {
        f32x4 xA, n0A, n1A;
        {
            const size_t fo = (size_t)tid * 4;
            xA  = ld(xb + fo);
            n0A = ldnt(nb0 + fo);
            n1A = ldnt(nb1 + fo);
        }
        #pragma unroll 2
        for (int p = 0; p < 49; ++p) {
            const f32x4 xC = xA, n0C = n0A, n1C = n1A;
            if (p < 48) {
                const size_t fo = (size_t)(p + 1) * 2048 + (size_t)tid * 4;
                xA  = ld(xb + fo);
                n0A = ldnt(nb0 + fo);
                n1A = ldnt(nb1 + fo);
            }
            const unsigned long long a0 = __ballot(n0C[0] < xC[0]);
            const unsigned long long a1 = __ballot(n0C[1] < xC[1]);
            const unsigned long long a2 = __ballot(n0C[2] < xC[2]);
            const unsigned long long a3 = __ballot(n0C[3] < xC[3]);
            const unsigned long long c0 = __ballot(n1C[0] < xC[0]);
            const unsigned long long c1 = __ballot(n1C[1] < xC[1]);
            const unsigned long long c2 = __ballot(n1C[2] < xC[2]);
            const unsigned long long c3 = __ballot(n1C[3] < xC[3]);
            if (lane < 16) {
                const int g = p * 128 + wave * 16 + u;            // < 6272
                const uint32_t row = ((uint32_t)g * 42800u) >> 21; // g/49 exact
                const int off = (int)row * 50 + (g - (int)row * 49);
                const uint32_t v0 = (uint32_t)((a0 >> (4 * u)) & 15ull)
                                  | ((uint32_t)((a1 >> (4 * u)) & 15ull) << 4)
                                  | ((uint32_t)((a2 >> (4 * u)) & 15ull) << 8)
                                  | ((uint32_t)((a3 >> (4 * u)) & 15ull) << 12);
                const uint32_t v1 = (uint32_t)((c0 >> (4 * u)) & 15ull)
                                  | ((uint32_t)((c1 >> (4 * u)) & 15ull) << 4)
                                  | ((uint32_t)((c2 >> (4 * u)) & 15ull) << 8)
                                  | ((uint32_t)((c3 >> (4 * u)) & 15ull) << 12);
                sB[0][off] = (unsigned short)v0;
                sB[1][off] = (unsigned short)v1;
            }
        }
    }
    __syncthreads();

    // ---- GEMM phase: wf fragment loaded once per kt, used for both t's ----
    const uint32_t* s0 = reinterpret_cast<const uint32_t*>(&sB[0][0]);
    const uint32_t* s1 = reinterpret_cast<const uint32_t*>(&sB[1][0]);
    const int qe0 = (lg & 1) * 2 + (lg >> 1) * 16;
    const int rowBase = (Mhalf * 64 + u) * 25;

    f32x4 acc[2][4][2];
    #pragma unroll
    for (int tt = 0; tt < 2; ++tt)
        #pragma unroll
        for (int mt = 0; mt < 4; ++mt)
            #pragma unroll
            for (int nt = 0; nt < 2; ++nt) acc[tt][mt][nt] = (f32x4){0, 0, 0, 0};

    #pragma unroll 2
    for (int kt = 0; kt < KT; ++kt) {
        bf16x8 bhi[2], blo[2];
        #pragma unroll
        for (int nt = 0; nt < 2; ++nt) {
            const size_t fo = (size_t)(kt * 8 + Nq * 2 + nt) * 1024 + lane * 8;
            bhi[nt] = *reinterpret_cast<const bf16x8*>(wf + fo);
            blo[nt] = *reinterpret_cast<const bf16x8*>(wf + fo + 512);
        }
        #pragma unroll
        for (int mt = 0; mt < 4; ++mt) {
            const int ro = rowBase + mt * 400 + kt;    // (Mhalf*64+mt*16+u)*25 + kt
            const uint32_t g0 = s0[ro];
            const uint32_t g1 = s1[ro];
            union { uint32_t uu[4]; bf16x8 vv; } pk0, pk1;
            #pragma unroll
            for (int d = 0; d < 4; ++d) {
                const int qe = qe0 + (d & 1) * 8 + (d >> 1);
                pk0.uu[d] = ((g0 >> qe) & 1u) * 0x3F80u | ((g0 >> (qe + 4)) & 1u) * 0x3F800000u;
                pk1.uu[d] = ((g1 >> qe) & 1u) * 0x3F80u | ((g1 >> (qe + 4)) & 1u) * 0x3F800000u;
            }
            #pragma unroll
            for (int nt = 0; nt < 2; ++nt) {
                acc[0][mt][nt] = __builtin_amdgcn_mfma_f32_16x16x32_bf16(pk0.vv, bhi[nt], acc[0][mt][nt], 0, 0, 0);
                acc[0][mt][nt] = __builtin_amdgcn_mfma_f32_16x16x32_bf16(pk0.vv, blo[nt], acc[0][mt][nt], 0, 0, 0);
                acc[1][mt][nt] = __builtin_amdgcn_mfma_f32_16x16x32_bf16(pk1.vv, bhi[nt], acc[1][mt][nt], 0, 0, 0);
                acc[1][mt][nt] = __builtin_amdgcn_mfma_f32_16x16x32_bf16(pk1.vv, blo[nt], acc[1][mt][nt], 0, 0, 0);
            }
        }
    }

    // ---- epilogue: H transposed [b][t][100]. C/D: col=u, row=lg*4+r ----
    #pragma unroll
    for (int tt = 0; tt < 2; ++tt) {
        const int t = 2 * tp + tt;
        #pragma unroll
        for (int mt = 0; mt < 4; ++mt) {
            const int rowG = b0 + Mhalf * 64 + mt * 16 + lg * 4;
            #pragma unroll
            for (int nt = 0; nt < 2; ++nt) {
                const int col = (Nq * 2 + nt) * 16 + u;
                if (col < DH) {
                    #pragma unroll
                    for (int r = 0; r < 4; ++r)
                        H[(size_t)(rowG + r) * (32 * DH) + t * DH + col] = acc[tt][mt][nt][r];
                }
            }
        }
    }
}

// ---------------- K2: IF scan over t + logits = cnt @ W2^T ----------------
// H transposed: row b = 3200 consecutive floats (t-major).
__global__ __launch_bounds__(256) void snn_scan(const float* __restrict__ H,
                                                const float* __restrict__ W2,
                                                float* __restrict__ out) {
    __shared__ float cbuf[2][104];
    __shared__ float w2s[1000];
    const int tid = threadIdx.x;
    const int r = tid >> 7, h = tid & 127;
    const size_t b = (size_t)blockIdx.x * 2 + r;
    for (int i = tid; i < 1000; i += 256) w2s[i] = W2[i];

    float cnt = 0.f;
    if (h < DH) {
        float hv[32];
        #pragma unroll
        for (int t = 0; t < 32; ++t) hv[t] = H[b * (32 * DH) + t * DH + h];
        float v = 0.f;
        #pragma unroll
        for (int t = 0; t < 32; ++t) {
            v += hv[t];
            float s = (v - 1.0f > 0.0f) ? 1.0f : 0.0f;  // exact reference semantics
            v -= s;
            cnt += s;
        }
    }
    if (h < DH) cbuf[r][h] = cnt;
    __syncthreads();
    if (tid < 20) {
        const int rr = tid / 10, o = tid % 10;
        float s = 0.f;
        for (int hh = 0; hh < DH; ++hh) s += cbuf[rr][hh] * w2s[o * DH + hh];
        out[((size_t)blockIdx.x * 2 + rr) * 10 + o] = s;
    }
}

extern "C" void kernel_launch(void* const* d_in, const int* in_sizes, int n_in,
                              void* d_out, int out_size, void* d_ws, size_t ws_size,
                              hipStream_t stream) {
    const float* x     = (const float*)d_in[0];   // [8192,784]
    const float* noise = (const float*)d_in[1];   // [32,8192,784]
    const float* W1    = (const float*)d_in[2];   // [100,784]
    const float* W2    = (const float*)d_in[3];   // [10,100]
    float* out = (float*)d_out;                   // [8192,10]

    unsigned short* wf = (unsigned short*)d_ws;                      // 400 KB W1 frags
    float* H = (float*)((char*)d_ws + (1u << 20));                   // 104.9 MB H (transposed)

    prep_w1<<<50, 256, 0, stream>>>(W1, wf);
    snn_gemm2<<<1024, 512, 0, stream>>>(x, noise, wf, H);
    snn_scan<<<4096, 256, 0, stream>>>(H, W2, out);
}